// Round 4
// baseline (3917.214 us; speedup 1.0000x reference)
//
#include <hip/hip_runtime.h>
#include <math.h>

#define N 64
#define GS 68   // LDS row stride (floats); 272 B rows, b128-aligned
#define MAX_ITER 5

__device__ __forceinline__ float rl(float x, int lane) {
    return __uint_as_float(__builtin_amdgcn_readlane(__float_as_uint(x), lane));
}

// One 64-thread wave per 64x64 SPD matrix.
// Phase 1 (LDS-free): Householder QR, lane t = column t of A, lane t = row t of Qt.
// Coefficients v_k[i] broadcast from lane k's registers via v_readlane (SGPR operand
// FMAs, no memory latency). Single fused pass per k: applies H_k to A-columns and
// Qt-rows AND computes step-k+1's dot products / pivot norm / captures from the
// post-update values. One batched register->LDS transpose per iteration feeds phase 2.
// Phase 2: lane t = row t of A_next = R*H0..H62 (A symmetric => rows feed next iter's
// columns). Epilogue: X = U diag(log clip(diag)) U^T.
__global__ __launch_bounds__(64, 3) void logm_kernel(const float* __restrict__ gin,
                                                     float* __restrict__ gout) {
    __shared__ __align__(16) float G[N * GS];
    const int t = threadIdx.x;
    const long b = blockIdx.x;
    const float* __restrict__ in = gin + b * (long)(N * N);
    float* __restrict__ out = gout + b * (long)(N * N);

    float a[N];   // phase 1: column t of A; phase 2: row t
    float qt[N];  // row t of Q_total

    #pragma unroll
    for (int i = 0; i < N; ++i) a[i] = in[i * N + t];
    #pragma unroll
    for (int i = 0; i < N; ++i) qt[i] = (i == t) ? 1.0f : 0.0f;

    float betaS = 0.f, v0S = 0.f, alS = 0.f;  // lane k stashes beta_k / v0_k / alpha_k

    for (int iter = 0; iter < MAX_ITER; ++iter) {
        // ---- prologue: dot(0) = sum_i c_i*a[i] (c from lane 0), norms, captures ----
        float dotA, dotQ, ssv, wA, wQ, x0;
        {
            float dA0 = 0.f, dA1 = 0.f, dQ0 = 0.f, dQ1 = 0.f, g0 = 0.f, g1 = 0.f;
            float cwA = 0.f, cwQ = 0.f, cx0 = 0.f;
            #pragma unroll
            for (int i = 0; i < N; ++i) {
                const float c = rl(a[i], 0);
                if (i & 1) { dA1 = fmaf(c, a[i], dA1); dQ1 = fmaf(c, qt[i], dQ1); g1 = fmaf(a[i], a[i], g1); }
                else       { dA0 = fmaf(c, a[i], dA0); dQ0 = fmaf(c, qt[i], dQ0); g0 = fmaf(a[i], a[i], g0); }
                if (i == 0) { cwA = a[0]; cwQ = qt[0]; cx0 = c; }
            }
            dotA = dA0 + dA1; dotQ = dQ0 + dQ1; ssv = g0 + g1;
            wA = cwA; wQ = cwQ; x0 = cx0;
        }

        // ---- fused factorization loop ----
        for (int k = 0; k < N - 1; ++k) {
            const float ss = rl(ssv, k);             // ||A[k:,k]||^2 (lane k's tail norm)
            const float nrm = sqrtf(ss);
            const float alpha = (x0 >= 0.f) ? -nrm : nrm;
            const float v0 = x0 - alpha;
            const float vtv = fmaf(v0, v0, ss - x0 * x0);
            const float beta = (vtv > 1e-30f) ? __fdividef(2.0f, vtv) : 0.f;
            // dot(k) included coefficient x0 at i=k; true coef is v0: da = dot - alpha*w
            const float da = fmaf(-alpha, wA, dotA);
            const float dq = fmaf(-alpha, wQ, dotQ);
            const float ca = beta * da;
            const float cq = beta * dq;
            const float caE = (t > k) ? ca : 0.f;    // freeze columns <= k (lane k keeps v_k)
            betaS = (t == k) ? beta : betaS;
            v0S   = (t == k) ? v0   : v0S;
            alS   = (t == k) ? alpha : alS;

            const int B0 = k & ~7;
            const int K1B = (k + 1) & ~7;
            float nA0 = 0.f, nA1 = 0.f, nQ0 = 0.f, nQ1 = 0.f, g0 = 0.f, g1 = 0.f;
            float nwA = 0.f, nwQ = 0.f, nx0 = 0.f;

            #pragma unroll
            for (int i0 = 0; i0 < N; i0 += 8) {
                if (i0 + 8 > k) {                     // uniform skip of dead blocks
                    const bool isB0 = (i0 == B0);
                    const bool hasK1 = (i0 == K1B);
                    #pragma unroll
                    for (int u = 0; u < 8; ++u) {
                        const int i = i0 + u;
                        float cu = rl(a[i], k);       // v_k[i] from lane k (uniform)
                        if (isB0) cu = (i > k) ? cu : ((i == k) ? v0 : 0.f);
                        a[i]  = fmaf(-caE, cu, a[i]);
                        qt[i] = fmaf(-cq,  cu, qt[i]);
                        float c2 = rl(a[i], k + 1);   // post-update: v_{k+1} candidate
                        if (isB0) c2 = (i > k) ? c2 : 0.f;
                        float av = a[i];
                        if (isB0) av = (i > k) ? av : 0.f;
                        if (u & 1) { nA1 = fmaf(c2, a[i], nA1); nQ1 = fmaf(c2, qt[i], nQ1); g1 = fmaf(av, av, g1); }
                        else       { nA0 = fmaf(c2, a[i], nA0); nQ0 = fmaf(c2, qt[i], nQ0); g0 = fmaf(av, av, g0); }
                        if (hasK1) {
                            const bool e = (i == k + 1);
                            nwA = e ? a[i]  : nwA;
                            nwQ = e ? qt[i] : nwQ;
                            nx0 = e ? c2    : nx0;
                        }
                    }
                }
            }
            dotA = nA0 + nA1; dotQ = nQ0 + nQ1; ssv = g0 + g1;
            wA = nwA; wQ = nwQ; x0 = nx0;
        }

        // ---- batched archive: lane t writes frozen column t -> G row t (transpose) ----
        #pragma unroll
        for (int i = 0; i < N; i += 4) {
            float4 w; w.x = a[i]; w.y = a[i + 1]; w.z = a[i + 2]; w.w = a[i + 3];
            *reinterpret_cast<float4*>(&G[t * GS + i]) = w;
        }
        // diag = alpha_t (R diagonal); lane 63's 1x1 block: diag is just a[63]
        G[t * GS + t] = (t == N - 1) ? a[N - 1] : alS;

        // ---- Phase 2: a[] <- row t of R, then A_next = R*H0..H62 (row-local) ----
        #pragma unroll
        for (int j = 0; j < N; ++j) {
            const float rj = G[j * GS + t];           // per-lane column read, conflict-free
            a[j] = (j >= t) ? rj : 0.f;
        }

        for (int k = 0; k < N - 1; ++k) {
            const float bk  = rl(betaS, k);
            const float v0k = rl(v0S, k);
            const int B0 = k & ~7;
            float d0 = 0.f, d1 = 0.f, d2 = 0.f, d3 = 0.f;
            #pragma unroll
            for (int j0 = 0; j0 < N; j0 += 8) {
                if (j0 + 8 > k) {
                    float4 c0 = *reinterpret_cast<const float4*>(&G[k * GS + j0]);
                    float4 c1 = *reinterpret_cast<const float4*>(&G[k * GS + j0 + 4]);
                    float c[8] = {c0.x, c0.y, c0.z, c0.w, c1.x, c1.y, c1.z, c1.w};
                    if (j0 == B0) {
                        #pragma unroll
                        for (int u = 0; u < 8; ++u) {
                            const int j = j0 + u;
                            c[u] = (j > k) ? c[u] : ((j == k) ? v0k : 0.f);
                        }
                    }
                    #pragma unroll
                    for (int u = 0; u < 8; ++u) {
                        const int j = j0 + u;
                        if      ((u & 3) == 0) d0 = fmaf(c[u], a[j], d0);
                        else if ((u & 3) == 1) d1 = fmaf(c[u], a[j], d1);
                        else if ((u & 3) == 2) d2 = fmaf(c[u], a[j], d2);
                        else                   d3 = fmaf(c[u], a[j], d3);
                    }
                }
            }
            const float cc = bk * ((d0 + d1) + (d2 + d3));
            #pragma unroll
            for (int j0 = 0; j0 < N; j0 += 8) {
                if (j0 + 8 > k) {
                    float4 c0 = *reinterpret_cast<const float4*>(&G[k * GS + j0]);
                    float4 c1 = *reinterpret_cast<const float4*>(&G[k * GS + j0 + 4]);
                    float c[8] = {c0.x, c0.y, c0.z, c0.w, c1.x, c1.y, c1.z, c1.w};
                    if (j0 == B0) {
                        #pragma unroll
                        for (int u = 0; u < 8; ++u) {
                            const int j = j0 + u;
                            c[u] = (j > k) ? c[u] : ((j == k) ? v0k : 0.f);
                        }
                    }
                    #pragma unroll
                    for (int u = 0; u < 8; ++u) {
                        const int j = j0 + u;
                        a[j] = fmaf(-cc, c[u], a[j]);
                    }
                }
            }
        }
        // a[] = row t of A_next = column t (symmetric) -> feeds next iteration directly.
    }

    // ---- Epilogue: sm = log(clip(diag)), w = sm .* U-row (into a[]), X = w . U^T ----
    #pragma unroll
    for (int l = 0; l < N; ++l) {
        const float dl = __shfl(a[l], l, 64);         // A[l][l]
        const float sml = __logf(fmaxf(dl, 1e-6f));
        a[l] = sml * qt[l];                           // w[l] = sm[l] * U[t][l]
    }
    #pragma unroll
    for (int l = 0; l < N; l += 4) {                  // U rows -> G (overwrite factorization)
        float4 w; w.x = qt[l]; w.y = qt[l + 1]; w.z = qt[l + 2]; w.w = qt[l + 3];
        *reinterpret_cast<float4*>(&G[t * GS + l]) = w;
    }
    #pragma unroll 2
    for (int j = 0; j < N; ++j) {                     // X[t][j]; store at [j][t] (X symmetric)
        float e0 = 0.f, e1 = 0.f, e2 = 0.f, e3 = 0.f;
        #pragma unroll
        for (int l = 0; l < N; l += 4) {
            float4 u4 = *reinterpret_cast<const float4*>(&G[j * GS + l]);
            e0 = fmaf(a[l + 0], u4.x, e0);
            e1 = fmaf(a[l + 1], u4.y, e1);
            e2 = fmaf(a[l + 2], u4.z, e2);
            e3 = fmaf(a[l + 3], u4.w, e3);
        }
        out[j * N + t] = (e0 + e1) + (e2 + e3);       // coalesced
    }
}

extern "C" void kernel_launch(void* const* d_in, const int* in_sizes, int n_in,
                              void* d_out, int out_size, void* d_ws, size_t ws_size,
                              hipStream_t stream) {
    const float* in = (const float*)d_in[0];
    float* out = (float*)d_out;
    const int batch = in_sizes[0] / (N * N);
    hipLaunchKernelGGL(logm_kernel, dim3(batch), dim3(64), 0, stream, in, out);
}

// Round 5
// 1392.456 us; speedup vs baseline: 2.8132x; 2.8132x over previous
//
#include <hip/hip_runtime.h>
#include <math.h>

#define N 64
#define GS 68   // LDS row stride (floats); 272 B rows, b128-aligned
#define MAX_ITER 5

__device__ __forceinline__ float rl(float x, int lane) {
    return __uint_as_float(__builtin_amdgcn_readlane(__float_as_uint(x), lane));
}

// One 64-thread wave per 64x64 SPD matrix. Registers:
//   a[]  : phase 1 = column t of A (freezes into v_t); phase 2 = readlane source of v_k
//   r[]  : phase 2 = row t of A_next = R*H0..H62
//   qt[] : row t of Q_total
// Phase 1 (LDS-free): fused Householder step — one register pass per k applies H_k to
// A-columns + Qt-rows and computes step k+1's dots via deferred-coefficient trick
// (ss = rl(dotA,k), x0 = rl(wA,k)). Phase 2 (LDS-free coefficients): after archiving
// columns to G (transpose for R-row init), zero each lane's upper column + plant v0 at
// the diagonal so readlane gives exact v_k — no patches, no corrections. A_next is
// symmetric, so phase-2 rows feed the next iteration's columns directly.
__global__ __launch_bounds__(64, 2) void logm_kernel(const float* __restrict__ gin,
                                                     float* __restrict__ gout) {
    __shared__ __align__(16) float G[N * GS];
    const int t = threadIdx.x;
    const long b = blockIdx.x;
    const float* __restrict__ in = gin + b * (long)(N * N);
    float* __restrict__ out = gout + b * (long)(N * N);

    float a[N], r[N], qt[N];

    #pragma unroll
    for (int i = 0; i < N; ++i) a[i] = in[i * N + t];
    #pragma unroll
    for (int i = 0; i < N; ++i) qt[i] = (i == t) ? 1.0f : 0.0f;

    float betaS = 0.f, v0S = 0.f, alS = 0.f;  // lane k stashes beta_k / v0_k / alpha_k

    for (int iter = 0; iter < MAX_ITER; ++iter) {
        // ================= Phase 1: Householder QR, fused register passes =================
        float dotA, dotQ, wA, wQ;
        {   // prologue: deferred dot for k=0 (raw coefficient x0 at i=0), w = row 0
            float dA0 = 0.f, dA1 = 0.f, dQ0 = 0.f, dQ1 = 0.f;
            #pragma unroll
            for (int i = 0; i < N; ++i) {
                const float c = rl(a[i], 0);
                if (i & 1) { dA1 = fmaf(c, a[i], dA1); dQ1 = fmaf(c, qt[i], dQ1); }
                else       { dA0 = fmaf(c, a[i], dA0); dQ0 = fmaf(c, qt[i], dQ0); }
            }
            dotA = dA0 + dA1; dotQ = dQ0 + dQ1;
            wA = a[0]; wQ = qt[0];
        }

        #pragma unroll
        for (int kb = 0; kb < 8; ++kb) {
            const int dkEnd = (kb == 7) ? 7 : 8;          // k stops at 62
            for (int dk = 0; dk < dkEnd; ++dk) {
                const int k = 8 * kb + dk;
                const int k1 = k + 1;
                const float ss = rl(dotA, k);             // tail norm ||A[k:,k]||^2
                const float x0 = rl(wA, k);               // A[k][k]
                const float nrm = sqrtf(ss);
                const float alpha = (x0 >= 0.f) ? -nrm : nrm;
                const float v0 = x0 - alpha;
                const float vtv = fmaf(v0, v0, ss - x0 * x0);
                const float beta = (vtv > 1e-30f) ? __fdividef(2.0f, vtv) : 0.f;
                const float ca = beta * fmaf(-alpha, wA, dotA);   // deferred-coef fix
                const float cq = beta * fmaf(-alpha, wQ, dotQ);
                const float caE = (t > k) ? ca : 0.f;     // freeze columns <= k
                betaS = (t == k) ? beta  : betaS;
                v0S   = (t == k) ? v0    : v0S;
                alS   = (t == k) ? alpha : alS;

                float nA0 = 0.f, nA1 = 0.f, nQ0 = 0.f, nQ1 = 0.f, nwA = 0.f, nwQ = 0.f;
                #pragma unroll
                for (int i0 = 8 * kb; i0 < N; i0 += 8) {  // compile-time range per kb
                    #pragma unroll
                    for (int u = 0; u < 8; ++u) {
                        const int i = i0 + u;
                        float cu = rl(a[i], k);           // v_k[i] from lane k
                        if (i0 == 8 * kb) cu = (i > k) ? cu : ((i == k) ? v0 : 0.f);
                        a[i]  = fmaf(-caE, cu, a[i]);
                        qt[i] = fmaf(-cq,  cu, qt[i]);
                        float c2 = rl(a[i], k1);          // post-update col k+1 (raw)
                        if (i0 == 8 * kb) c2 = (i > k) ? c2 : 0.f;
                        if (u & 1) { nA1 = fmaf(c2, a[i], nA1); nQ1 = fmaf(c2, qt[i], nQ1); }
                        else       { nA0 = fmaf(c2, a[i], nA0); nQ0 = fmaf(c2, qt[i], nQ0); }
                        // capture row k+1 (needed as wA/wQ next step); k1 is in block kb
                        // (u>0) or first slot of block kb+1 (dk==7)
                        if ((i0 == 8 * kb && u > 0) || (kb < 7 && i0 == 8 * kb + 8 && u == 0)) {
                            const bool e = (i == k1);
                            nwA = e ? a[i]  : nwA;
                            nwQ = e ? qt[i] : nwQ;
                        }
                    }
                }
                dotA = nA0 + nA1; dotQ = nQ0 + nQ1; wA = nwA; wQ = nwQ;
            }
        }

        // ============ Archive columns -> G rows (transpose); diag = alpha ============
        #pragma unroll
        for (int i = 0; i < N; i += 4) {
            float4 w; w.x = a[i]; w.y = a[i + 1]; w.z = a[i + 2]; w.w = a[i + 3];
            *reinterpret_cast<float4*>(&G[t * GS + i]) = w;
        }
        G[t * GS + t] = (t == N - 1) ? a[N - 1] : alS;

        // ==== Phase 2 init: r = row t of R; canonicalize a[] to exact v_t; k=0 dot ====
        float dR, wRv;
        {
            float d0 = 0.f, d1 = 0.f;
            #pragma unroll
            for (int j = 0; j < N; ++j) {
                const float g = G[j * GS + t];            // R[t][j] (per-lane col read)
                const float rj = (j >= t) ? g : 0.f;
                r[j] = rj;
                // lane t's column becomes exact v_t: zeros above diag, v0 at diag
                a[j] = (j == t) ? v0S : ((j < t) ? 0.f : a[j]);
                const float c = rl(a[j], 0);              // true v_0[j]
                if (j & 1) d1 = fmaf(c, rj, d1); else d0 = fmaf(c, rj, d0);
            }
            dR = d0 + d1; wRv = 0.f; (void)wRv;
        }

        // ============ Phase 2: r <- r * H0..H62, fused next-dot (true coefs) ============
        for (int k = 0; k < N - 1; ++k) {
            const int k1 = k + 1;
            const float cc = rl(betaS, k) * dR;           // dR is the true dot (exact v_k)
            float nD0 = 0.f, nD1 = 0.f;
            #pragma unroll
            for (int i0 = 0; i0 < N; i0 += 8) {
                if (i0 + 8 > k) {                         // uniform skip of dead blocks
                    #pragma unroll
                    for (int u = 0; u < 8; ++u) {
                        const int j = i0 + u;
                        const float cu = rl(a[j], k);     // exact v_k[j] (incl. zeros/v0)
                        r[j] = fmaf(-cc, cu, r[j]);
                        const float c2 = rl(a[j], k1);    // exact v_{k+1}[j]
                        if (u & 1) nD1 = fmaf(c2, r[j], nD1);
                        else       nD0 = fmaf(c2, r[j], nD0);
                    }
                }
            }
            dR = nD0 + nD1;
        }
        #pragma unroll
        for (int j = 0; j < N; ++j) a[j] = r[j];          // symmetric: rows -> next cols
    }

    // ======= Epilogue: sm = log(clip(diag)), w = sm .* U-row, X = w . U^T =======
    #pragma unroll
    for (int l = 0; l < N; ++l) {
        const float dl = rl(a[l], l);                     // A5[l][l]
        const float sml = __logf(fmaxf(dl, 1e-6f));
        a[l] = sml * qt[l];                               // w[l] = sm[l] * U[t][l]
    }
    #pragma unroll
    for (int l = 0; l < N; l += 4) {                      // U rows -> G
        float4 w; w.x = qt[l]; w.y = qt[l + 1]; w.z = qt[l + 2]; w.w = qt[l + 3];
        *reinterpret_cast<float4*>(&G[t * GS + l]) = w;
    }
    #pragma unroll 2
    for (int j = 0; j < N; ++j) {                         // X[t][j]; store [j][t] (symmetric)
        float e0 = 0.f, e1 = 0.f, e2 = 0.f, e3 = 0.f;
        #pragma unroll
        for (int l = 0; l < N; l += 4) {
            float4 u4 = *reinterpret_cast<const float4*>(&G[j * GS + l]);
            e0 = fmaf(a[l + 0], u4.x, e0);
            e1 = fmaf(a[l + 1], u4.y, e1);
            e2 = fmaf(a[l + 2], u4.z, e2);
            e3 = fmaf(a[l + 3], u4.w, e3);
        }
        out[j * N + t] = (e0 + e1) + (e2 + e3);           // coalesced
    }
}

extern "C" void kernel_launch(void* const* d_in, const int* in_sizes, int n_in,
                              void* d_out, int out_size, void* d_ws, size_t ws_size,
                              hipStream_t stream) {
    const float* in = (const float*)d_in[0];
    float* out = (float*)d_out;
    const int batch = in_sizes[0] / (N * N);
    hipLaunchKernelGGL(logm_kernel, dim3(batch), dim3(64), 0, stream, in, out);
}